// Round 2
// baseline (13500.925 us; speedup 1.0000x reference)
//
#include <hip/hip_runtime.h>
#include <math.h>

#define D_DIM 1024
#define H_DIM 1024
#define N_BATCH 128
#define T_STEPS 512

// ---------------------------------------------------------------------------
// Phase 1: out[M,H] = X[M,D] @ Wx[D,H] + b   (M = N*T = 65536), fp32
// 64x64 tile, BK=16, 256 threads, 4x4 micro-tile per thread.
// ---------------------------------------------------------------------------
__global__ __launch_bounds__(256) void gemm_xw(const float* __restrict__ X,
                                               const float* __restrict__ Wx,
                                               const float* __restrict__ b,
                                               float* __restrict__ out) {
    __shared__ float sa[16][68];  // sa[k][m], padded so float4 reads are 16B-aligned
    __shared__ float sb[16][64];  // sb[k][n]

    const int m0 = blockIdx.y * 64;
    const int n0 = blockIdx.x * 64;
    const int tid = threadIdx.x;
    const int tx = tid & 15;   // col group -> cols tx*4..tx*4+3
    const int ty = tid >> 4;   // row group -> rows ty*4..ty*4+3

    float acc[4][4] = {};

    for (int k0 = 0; k0 < D_DIM; k0 += 16) {
        // Load A tile: 64 rows x 16 k  (1024 elts, 4 per thread), store transposed
        #pragma unroll
        for (int i = 0; i < 4; ++i) {
            int e = tid + 256 * i;           // 0..1023
            int row = e >> 4, col = e & 15;  // row: m-local, col: k-local
            sa[col][row] = X[(long)(m0 + row) * D_DIM + (k0 + col)];
        }
        // Load B tile: 16 k x 64 cols (1024 elts, 4 per thread)
        #pragma unroll
        for (int i = 0; i < 4; ++i) {
            int e = tid + 256 * i;
            int row = e >> 6, col = e & 63;  // row: k-local, col: n-local
            sb[row][col] = Wx[(long)(k0 + row) * H_DIM + (n0 + col)];
        }
        __syncthreads();

        #pragma unroll
        for (int kk = 0; kk < 16; ++kk) {
            float4 ra = *reinterpret_cast<const float4*>(&sa[kk][ty * 4]);
            float4 rb = *reinterpret_cast<const float4*>(&sb[kk][tx * 4]);
            float rav[4] = {ra.x, ra.y, ra.z, ra.w};
            float rbv[4] = {rb.x, rb.y, rb.z, rb.w};
            #pragma unroll
            for (int i = 0; i < 4; ++i)
                #pragma unroll
                for (int j = 0; j < 4; ++j)
                    acc[i][j] += rav[i] * rbv[j];
        }
        __syncthreads();
    }

    #pragma unroll
    for (int i = 0; i < 4; ++i) {
        int r = m0 + ty * 4 + i;
        #pragma unroll
        for (int j = 0; j < 4; ++j) {
            int c = n0 + tx * 4 + j;
            out[(long)r * H_DIM + c] = acc[i][j] + b[c];
        }
    }
}

// ---------------------------------------------------------------------------
// Phase 2: one timestep.  out slice t currently holds xW[:,t,:]; replace with
//   h_t = tanh(h_{t-1} @ Wh + xW_t)
// Block computes 32 rows x 16 cols.  Grid: (1024/16) x (128/32) = 64 x 4 = 256.
// ---------------------------------------------------------------------------
#define SR 32
#define SC 16
__global__ __launch_bounds__(256) void rnn_step(const float* __restrict__ hprev,
                                                long hp_stride,
                                                const float* __restrict__ Wh,
                                                float* __restrict__ out,
                                                long out_stride) {
    __shared__ float sh[64][SR + 2];  // sh[k][row]; +2 pad keeps float2 aligned
    __shared__ float sw[64][SC + 1];  // sw[k][col]

    const int r0 = blockIdx.y * SR;
    const int c0 = blockIdx.x * SC;
    const int tid = threadIdx.x;
    const int tc = tid & 15;   // output col within tile
    const int tr = tid >> 4;   // row group: rows tr*2, tr*2+1

    float acc0 = 0.f, acc1 = 0.f;

    for (int k0 = 0; k0 < H_DIM; k0 += 64) {
        // h chunk: 32 rows x 64 k = 2048 elts, 8 per thread
        #pragma unroll
        for (int i = 0; i < 8; ++i) {
            int e = tid + 256 * i;           // 0..2047
            int row = e >> 6, col = e & 63;  // row: batch-local, col: k-local
            sh[col][row] = hprev[(long)(r0 + row) * hp_stride + (k0 + col)];
        }
        // Wh chunk: 64 k x 16 cols = 1024 elts, 4 per thread
        #pragma unroll
        for (int i = 0; i < 4; ++i) {
            int e = tid + 256 * i;
            int row = e >> 4, col = e & 15;  // row: k-local, col: n-local
            sw[row][col] = Wh[(long)(k0 + row) * H_DIM + (c0 + col)];
        }
        __syncthreads();

        #pragma unroll
        for (int kk = 0; kk < 64; ++kk) {
            float w = sw[kk][tc];
            float2 h2 = *reinterpret_cast<const float2*>(&sh[kk][tr * 2]);
            acc0 += h2.x * w;
            acc1 += h2.y * w;
        }
        __syncthreads();
    }

    long o0 = (long)(r0 + tr * 2) * out_stride + (c0 + tc);
    long o1 = o0 + out_stride;
    out[o0] = tanhf(acc0 + out[o0]);
    out[o1] = tanhf(acc1 + out[o1]);
}

// ---------------------------------------------------------------------------
extern "C" void kernel_launch(void* const* d_in, const int* in_sizes, int n_in,
                              void* d_out, int out_size, void* d_ws, size_t ws_size,
                              hipStream_t stream) {
    const float* x  = (const float*)d_in[0];  // (N, T, D)
    const float* h0 = (const float*)d_in[1];  // (N, H)
    const float* Wx = (const float*)d_in[2];  // (D, H)
    const float* Wh = (const float*)d_in[3];  // (H, H)
    const float* b  = (const float*)d_in[4];  // (H,)
    float* out = (float*)d_out;               // (N, T, H)

    // Phase 1: out <- x @ Wx + b  (flattened rows m = n*T + t matches out layout)
    dim3 g1(H_DIM / 64, (N_BATCH * T_STEPS) / 64);
    gemm_xw<<<g1, 256, 0, stream>>>(x, Wx, b, out);

    // Phase 2: sequential scan, in place over out slices
    dim3 g2(H_DIM / SC, N_BATCH / SR);
    const long ostride = (long)T_STEPS * H_DIM;
    // t = 0: h_prev = h0 (row stride H)
    rnn_step<<<g2, 256, 0, stream>>>(h0, (long)H_DIM, Wh, out, ostride);
    for (int t = 1; t < T_STEPS; ++t) {
        rnn_step<<<g2, 256, 0, stream>>>(out + (long)(t - 1) * H_DIM, ostride,
                                         Wh, out + (long)t * H_DIM, ostride);
    }
}